// Round 3
// baseline (4274.567 us; speedup 1.0000x reference)
//
#include <hip/hip_runtime.h>
#include <hip/hip_bf16.h>

// HANConv (HANModel). Defensive round: runtime dtype detection (bf16 vs f32
// tensors, int32 vs int64 indices), sanitized loads, clamped indices,
// ws_size-aware chunked scatter accumulation. f32 compute throughout.

#define HEADS 4
#define DH 32
#define HID 128
#define IN_F 128
#define OUT_F 64
#define NEG 0.2f

typedef unsigned short u16;
typedef unsigned int u32;

__device__ __forceinline__ float us2f(u16 u){ return __uint_as_float(((u32)u) << 16); }
__device__ __forceinline__ u16 f2us(float f){            // f32 -> bf16 RNE
  u32 u = __float_as_uint(f);
  u += 0x7fffu + ((u >> 16) & 1u);
  return (u16)(u >> 16);
}
__device__ __forceinline__ float fin(float v){ return (fabsf(v) < 1e30f) ? v : 0.f; }
// width-adaptive sanitized loads from raw input tensors
__device__ __forceinline__ float ldf(const void* p, size_t i, int wide){
  float v = wide ? ((const float*)p)[i] : us2f(((const u16*)p)[i]);
  return fin(v);
}
__device__ __forceinline__ u16 ld16(const void* p, size_t i, int wide){
  if (wide) return f2us(fin(((const float*)p)[i]));
  u16 r = ((const u16*)p)[i];
  return (((r >> 7) & 0xff) == 0xff) ? (u16)0 : r;   // kill bf16 NaN/Inf
}
// order-preserving float<->uint for atomicMax-as-float-max (enc>0 always)
__device__ __forceinline__ u32 enc_f(float x){
  u32 u = __float_as_uint(x);
  return (u & 0x80000000u) ? ~u : (u | 0x80000000u);
}
__device__ __forceinline__ float dec_f(u32 u){
  u32 b = (u & 0x80000000u) ? (u & 0x7fffffffu) : ~u;
  return __uint_as_float(b);
}
__device__ __forceinline__ int ld_idx(const int* __restrict__ p, int e, int sh, int n){
  int v = p[(size_t)e << sh];
  return v < 0 ? 0 : (v >= n ? n - 1 : v);
}

// ---- detection kernels -----------------------------------------------------
// bf16-plausibility of first n u16 words: bf16 data ~100%, f32-as-bf16 ~60%.
__global__ void detect_float_width(const u16* __restrict__ x, int n, int* __restrict__ flag)
{
  __shared__ int cnt;
  if (threadIdx.x == 0) cnt = 0;
  __syncthreads();
  int local = 0;
  for (int i = threadIdx.x; i < n; i += blockDim.x) {
    int e = (x[i] >> 7) & 0xff;
    if (e == 0 || (e >= 100 && e <= 150)) local++;
  }
  atomicAdd(&cnt, local);
  __syncthreads();
  if (threadIdx.x == 0) *flag = (cnt < (n * 9) / 10) ? 1 : 0;  // 1 = f32
}
// int64 indices have all odd int32 words zero (values < 2^31).
__global__ void detect_idx_width(const int* __restrict__ s, int n, int* __restrict__ flag)
{
  __shared__ int any;
  if (threadIdx.x == 0) any = 0;
  __syncthreads();
  for (int i = threadIdx.x; i < n; i += blockDim.x)
    if (s[2 * i + 1] != 0) atomicOr(&any, 1);
  __syncthreads();
  if (threadIdx.x == 0) *flag = any ? 0 : 1;                   // 1 = int64
}

// ---- projection: h[n,c] = x[n,:] @ W[:,c] + b[c]  (->bf16) -----------------
__global__ __launch_bounds__(256) void proj_kernel(
    const void* __restrict__ x, const void* __restrict__ W,
    const void* __restrict__ b, u16* __restrict__ h, int N,
    const int* __restrict__ flag_f)
{
  const int wide = *flag_f;
  __shared__ u16 Wl[IN_F * HID];      // 32 KB
  __shared__ float xt[IN_F][40];      // 20 KB
  for (int i = threadIdx.x; i < IN_F * HID; i += 256) Wl[i] = ld16(W, i, wide);
  const int base = blockIdx.x * 32;
  for (int i = threadIdx.x; i < 32 * IN_F; i += 256) {
    int node = i >> 7, k = i & 127;
    int nn = base + node;
    xt[k][node] = (nn < N) ? ldf(x, (size_t)nn * IN_F + k, wide) : 0.f;
  }
  __syncthreads();
  const int ng = threadIdx.x & 7;
  const int cg = threadIdx.x >> 3;
  float acc[4][4];
#pragma unroll
  for (int r = 0; r < 4; ++r)
#pragma unroll
    for (int j = 0; j < 4; ++j) acc[r][j] = ldf(b, cg * 4 + j, wide);
#pragma unroll 4
  for (int k = 0; k < IN_F; ++k) {
    const float4 xv = *(const float4*)&xt[k][ng * 4];
    const ushort4 wv = *(const ushort4*)&Wl[k * HID + cg * 4];
    const float w0 = us2f(wv.x), w1 = us2f(wv.y), w2 = us2f(wv.z), w3 = us2f(wv.w);
    acc[0][0] += xv.x * w0; acc[0][1] += xv.x * w1; acc[0][2] += xv.x * w2; acc[0][3] += xv.x * w3;
    acc[1][0] += xv.y * w0; acc[1][1] += xv.y * w1; acc[1][2] += xv.y * w2; acc[1][3] += xv.y * w3;
    acc[2][0] += xv.z * w0; acc[2][1] += xv.z * w1; acc[2][2] += xv.z * w2; acc[2][3] += xv.z * w3;
    acc[3][0] += xv.w * w0; acc[3][1] += xv.w * w1; acc[3][2] += xv.w * w2; acc[3][3] += xv.w * w3;
  }
#pragma unroll
  for (int r = 0; r < 4; ++r) {
    int nn = base + ng * 4 + r;
    if (nn < N) {
      ushort4 o;
      o.x = f2us(acc[r][0]); o.y = f2us(acc[r][1]);
      o.z = f2us(acc[r][2]); o.w = f2us(acc[r][3]);
      *(ushort4*)&h[(size_t)nn * HID + cg * 4] = o;
    }
  }
}

// ---- per-node logits for two att vectors -----------------------------------
__global__ __launch_bounds__(256) void compute_a2(
    const u16* __restrict__ h, const void* __restrict__ att1,
    const void* __restrict__ att2, float* __restrict__ a1,
    float* __restrict__ a2, int N, const int* __restrict__ flag_f)
{
  const int wide = *flag_f;
  __shared__ float s1[HID], s2[HID];
  if (threadIdx.x < HID) {
    s1[threadIdx.x] = ldf(att1, threadIdx.x, wide);
    s2[threadIdx.x] = ldf(att2, threadIdx.x, wide);
  }
  __syncthreads();
  int t = blockIdx.x * 256 + threadIdx.x;
  if (t >= N * HEADS) return;
  int n = t >> 2, hh = t & 3;
  const u16* p = h + (size_t)n * HID + hh * DH;
  float acc1 = 0.f, acc2 = 0.f;
#pragma unroll
  for (int d = 0; d < DH; ++d) {
    float f = us2f(p[d]);
    acc1 += f * s1[hh * DH + d];
    acc2 += f * s2[hh * DH + d];
  }
  a1[t] = acc1;
  a2[t] = acc2;
}

// ---- edge passes -----------------------------------------------------------
__global__ __launch_bounds__(256) void edge_pass1(
    const int* __restrict__ src, const int* __restrict__ dst,
    const float* __restrict__ a_s, const float* __restrict__ a_d,
    u32* __restrict__ m_enc, int E4, const int* __restrict__ flag_i,
    int Ns, int Nd)
{
  int t = blockIdx.x * 256 + threadIdx.x;
  if (t >= E4) return;
  int e = t >> 2, hh = t & 3;
  int sh = *flag_i;
  int s = ld_idx(src, e, sh, Ns), d = ld_idx(dst, e, sh, Nd);
  float al = a_s[s * HEADS + hh] + a_d[d * HEADS + hh];
  al = (al > 0.f) ? al : NEG * al;
  atomicMax(&m_enc[d * HEADS + hh], enc_f(al));
}

__global__ __launch_bounds__(256) void edge_pass2(
    const int* __restrict__ src, const int* __restrict__ dst,
    const float* __restrict__ a_s, const float* __restrict__ a_d,
    const u32* __restrict__ m_enc, float* __restrict__ den, int E4,
    const int* __restrict__ flag_i, int Ns, int Nd)
{
  int t = blockIdx.x * 256 + threadIdx.x;
  if (t >= E4) return;
  int e = t >> 2, hh = t & 3;
  int sh = *flag_i;
  int s = ld_idx(src, e, sh, Ns), d = ld_idx(dst, e, sh, Nd);
  float al = a_s[s * HEADS + hh] + a_d[d * HEADS + hh];
  al = (al > 0.f) ? al : NEG * al;
  float ex = __expf(al - dec_f(m_enc[d * HEADS + hh]));
  atomicAdd(&den[d * HEADS + hh], ex);
}

// wave per edge, lane = 2 channels; only dst in [lo,hi) accumulated into
// o (chunk buffer, row 0 == node lo).
__global__ __launch_bounds__(256) void edge_pass3(
    const int* __restrict__ src, const int* __restrict__ dst,
    const float* __restrict__ a_s, const float* __restrict__ a_d,
    const u32* __restrict__ m_enc, const float* __restrict__ den,
    const u16* __restrict__ h_src, float* __restrict__ o, int E,
    const int* __restrict__ flag_i, int Ns, int Nd, int lo, int hi)
{
  int gid = blockIdx.x * 256 + threadIdx.x;
  int e = gid >> 6;
  if (e >= E) return;
  int lane = gid & 63;
  int sh = *flag_i;
  int d = ld_idx(dst, e, sh, Nd);
  if (d < lo || d >= hi) return;
  int s = ld_idx(src, e, sh, Ns);
  int hh = lane >> 4;
  float al = a_s[s * HEADS + hh] + a_d[d * HEADS + hh];
  al = (al > 0.f) ? al : NEG * al;
  float ex = __expf(al - dec_f(m_enc[d * HEADS + hh]));
  float w = ex / (den[d * HEADS + hh] + 1e-16f);
  const u16* hp = h_src + (size_t)s * HID + 2 * lane;
  float* op = o + (size_t)(d - lo) * HID + 2 * lane;
  atomicAdd(op, w * us2f(hp[0]));
  atomicAdd(op + 1, w * us2f(hp[1]));
}

// ---- semantic colsum over a chunk: S[c] += sum_n tanh(relu(o)@Wk + bk) -----
__global__ __launch_bounds__(256) void colsum_chunk(
    const float* __restrict__ o, int rows, const void* __restrict__ Wk,
    const void* __restrict__ bk, float* __restrict__ S,
    const int* __restrict__ flag_f)
{
  const int wide = *flag_f;
  __shared__ u16 Wl[HID * HID];   // 32 KB
  __shared__ float xt[HID][40];   // 20 KB
  for (int i = threadIdx.x; i < HID * HID; i += 256) Wl[i] = ld16(Wk, i, wide);
  const int ng = threadIdx.x & 7, cg = threadIdx.x >> 3;
  float bc[4], sum[4] = {0.f, 0.f, 0.f, 0.f};
#pragma unroll
  for (int j = 0; j < 4; ++j) bc[j] = ldf(bk, cg * 4 + j, wide);

  int ntiles = (rows + 31) >> 5;
  for (int t = blockIdx.x; t < ntiles; t += gridDim.x) {
    int base = t << 5;
    __syncthreads();
    for (int i = threadIdx.x; i < 32 * HID; i += 256) {
      int node = i >> 7, k = i & 127;
      int nn = base + node;
      xt[k][node] = (nn < rows) ? fmaxf(o[(size_t)nn * HID + k], 0.f) : 0.f;
    }
    __syncthreads();
    float acc[4][4];
#pragma unroll
    for (int r = 0; r < 4; ++r)
#pragma unroll
      for (int j = 0; j < 4; ++j) acc[r][j] = bc[j];
#pragma unroll 4
    for (int k = 0; k < HID; ++k) {
      const float4 xv = *(const float4*)&xt[k][ng * 4];
      const ushort4 wv = *(const ushort4*)&Wl[k * HID + cg * 4];
      const float w0 = us2f(wv.x), w1 = us2f(wv.y), w2 = us2f(wv.z), w3 = us2f(wv.w);
      acc[0][0] += xv.x * w0; acc[0][1] += xv.x * w1; acc[0][2] += xv.x * w2; acc[0][3] += xv.x * w3;
      acc[1][0] += xv.y * w0; acc[1][1] += xv.y * w1; acc[1][2] += xv.y * w2; acc[1][3] += xv.y * w3;
      acc[2][0] += xv.z * w0; acc[2][1] += xv.z * w1; acc[2][2] += xv.z * w2; acc[2][3] += xv.z * w3;
      acc[3][0] += xv.w * w0; acc[3][1] += xv.w * w1; acc[3][2] += xv.w * w2; acc[3][3] += xv.w * w3;
    }
#pragma unroll
    for (int r = 0; r < 4; ++r) {
      if (base + ng * 4 + r < rows) {
#pragma unroll
        for (int j = 0; j < 4; ++j) sum[j] += tanhf(acc[r][j]);
      }
    }
  }
#pragma unroll
  for (int j = 0; j < 4; ++j) {
    float v = sum[j];
    v += __shfl_xor(v, 1);
    v += __shfl_xor(v, 2);
    v += __shfl_xor(v, 4);
    if (ng == 0) atomicAdd(&S[cg * 4 + j], v);
  }
}

// ---- P = relu(o_chunk) @ Wlin  (no bias) -> bf16 [rows, OUT_F] -------------
__global__ __launch_bounds__(256) void linW_chunk(
    const float* __restrict__ o, int rows, const void* __restrict__ Wlin,
    u16* __restrict__ P, const int* __restrict__ flag_f)
{
  const int wide = *flag_f;
  __shared__ u16 Wl[HID * OUT_F];   // 16 KB
  __shared__ float xt[HID][68];     // 34.8 KB
  for (int i = threadIdx.x; i < HID * OUT_F; i += 256) Wl[i] = ld16(Wlin, i, wide);
  const int base = blockIdx.x * 64;
  for (int i = threadIdx.x; i < 64 * HID; i += 256) {
    int node = i >> 7, k = i & 127;
    int nn = base + node;
    xt[k][node] = (nn < rows) ? fmaxf(o[(size_t)nn * HID + k], 0.f) : 0.f;
  }
  __syncthreads();
  const int ng = threadIdx.x & 15;
  const int cg = threadIdx.x >> 4;
  float acc[4][4];
#pragma unroll
  for (int r = 0; r < 4; ++r)
#pragma unroll
    for (int j = 0; j < 4; ++j) acc[r][j] = 0.f;
#pragma unroll 4
  for (int k = 0; k < HID; ++k) {
    const float4 xv = *(const float4*)&xt[k][ng * 4];
    const ushort4 wv = *(const ushort4*)&Wl[k * OUT_F + cg * 4];
    const float w0 = us2f(wv.x), w1 = us2f(wv.y), w2 = us2f(wv.z), w3 = us2f(wv.w);
    acc[0][0] += xv.x * w0; acc[0][1] += xv.x * w1; acc[0][2] += xv.x * w2; acc[0][3] += xv.x * w3;
    acc[1][0] += xv.y * w0; acc[1][1] += xv.y * w1; acc[1][2] += xv.y * w2; acc[1][3] += xv.y * w3;
    acc[2][0] += xv.z * w0; acc[2][1] += xv.z * w1; acc[2][2] += xv.z * w2; acc[2][3] += xv.z * w3;
    acc[3][0] += xv.w * w0; acc[3][1] += xv.w * w1; acc[3][2] += xv.w * w2; acc[3][3] += xv.w * w3;
  }
#pragma unroll
  for (int r = 0; r < 4; ++r) {
    int nn = base + ng * 4 + r;
    if (nn < rows) {
      ushort4 ov;
      ov.x = f2us(acc[r][0]); ov.y = f2us(acc[r][1]);
      ov.z = f2us(acc[r][2]); ov.w = f2us(acc[r][3]);
      *(ushort4*)&P[(size_t)nn * OUT_F + cg * 4] = ov;
    }
  }
}

// ---- author out chunk: y = relu(o)@Wlin + blin  (width-adaptive store) -----
__global__ __launch_bounds__(256) void final_author_chunk(
    const float* __restrict__ o, int rows, int node0,
    const void* __restrict__ Wlin, const void* __restrict__ blin,
    void* __restrict__ out, const int* __restrict__ flag_f)
{
  const int wide = *flag_f;
  __shared__ u16 Wl[HID * OUT_F];
  __shared__ float xt[HID][68];
  for (int i = threadIdx.x; i < HID * OUT_F; i += 256) Wl[i] = ld16(Wlin, i, wide);
  const int base = blockIdx.x * 64;
  for (int i = threadIdx.x; i < 64 * HID; i += 256) {
    int node = i >> 7, k = i & 127;
    int nn = base + node;
    xt[k][node] = (nn < rows) ? fmaxf(o[(size_t)nn * HID + k], 0.f) : 0.f;
  }
  __syncthreads();
  const int ng = threadIdx.x & 15;
  const int cg = threadIdx.x >> 4;
  float acc[4][4];
#pragma unroll
  for (int r = 0; r < 4; ++r)
#pragma unroll
    for (int j = 0; j < 4; ++j) acc[r][j] = ldf(blin, cg * 4 + j, wide);
#pragma unroll 4
  for (int k = 0; k < HID; ++k) {
    const float4 xv = *(const float4*)&xt[k][ng * 4];
    const ushort4 wv = *(const ushort4*)&Wl[k * OUT_F + cg * 4];
    const float w0 = us2f(wv.x), w1 = us2f(wv.y), w2 = us2f(wv.z), w3 = us2f(wv.w);
    acc[0][0] += xv.x * w0; acc[0][1] += xv.x * w1; acc[0][2] += xv.x * w2; acc[0][3] += xv.x * w3;
    acc[1][0] += xv.y * w0; acc[1][1] += xv.y * w1; acc[1][2] += xv.y * w2; acc[1][3] += xv.y * w3;
    acc[2][0] += xv.z * w0; acc[2][1] += xv.z * w1; acc[2][2] += xv.z * w2; acc[2][3] += xv.z * w3;
    acc[3][0] += xv.w * w0; acc[3][1] += xv.w * w1; acc[3][2] += xv.w * w2; acc[3][3] += xv.w * w3;
  }
#pragma unroll
  for (int r = 0; r < 4; ++r) {
    int nn = base + ng * 4 + r;
    if (nn < rows) {
      size_t oi = (size_t)(node0 + nn) * OUT_F + cg * 4;
      if (wide) {
        float4 ov = {acc[r][0], acc[r][1], acc[r][2], acc[r][3]};
        *(float4*)&((float*)out)[oi] = ov;
      } else {
        ushort4 ov;
        ov.x = f2us(acc[r][0]); ov.y = f2us(acc[r][1]);
        ov.z = f2us(acc[r][2]); ov.w = f2us(acc[r][3]);
        *(ushort4*)&((u16*)out)[oi] = ov;
      }
    }
  }
}

// ---- semantic softmax ------------------------------------------------------
__global__ void score_softmax(const float* __restrict__ S, const void* __restrict__ q,
                              float* __restrict__ attn, float invN,
                              const int* __restrict__ flag_f)
{
  if (threadIdx.x == 0 && blockIdx.x == 0) {
    const int wide = *flag_f;
    float s0 = 0.f, s1 = 0.f;
    for (int c = 0; c < HID; ++c) {
      float qc = ldf(q, c, wide);
      s0 += qc * S[c] * invN;
      s1 += qc * S[HID + c] * invN;
    }
    float m = fmaxf(s0, s1);
    float e0 = __expf(s0 - m), e1 = __expf(s1 - m);
    attn[0] = e0 / (e0 + e1);
    attn[1] = e1 / (e0 + e1);
  }
}

// ---- paper out: y = a0*Pw + a1*Pc + blin  (elem_off = NA*OUT_F) ------------
__global__ __launch_bounds__(256) void combine_paper(
    const u16* __restrict__ Pw, const u16* __restrict__ Pc,
    const float* __restrict__ attn, const void* __restrict__ blin,
    void* __restrict__ out, size_t elem_off, int N,
    const int* __restrict__ flag_f)
{
  int t = blockIdx.x * 256 + threadIdx.x;
  if (t >= N * 16) return;
  const int wide = *flag_f;
  int n = t >> 4, cq = t & 15;
  const float a0 = attn[0], a1 = attn[1];
  size_t i = (size_t)n * OUT_F + cq * 4;
  ushort4 w4 = *(const ushort4*)&Pw[i];
  ushort4 c4 = *(const ushort4*)&Pc[i];
  float v[4];
  v[0] = a0 * us2f(w4.x) + a1 * us2f(c4.x) + ldf(blin, cq * 4 + 0, wide);
  v[1] = a0 * us2f(w4.y) + a1 * us2f(c4.y) + ldf(blin, cq * 4 + 1, wide);
  v[2] = a0 * us2f(w4.z) + a1 * us2f(c4.z) + ldf(blin, cq * 4 + 2, wide);
  v[3] = a0 * us2f(w4.w) + a1 * us2f(c4.w) + ldf(blin, cq * 4 + 3, wide);
  size_t oi = elem_off + i;
  if (wide) {
    float4 ov = {v[0], v[1], v[2], v[3]};
    *(float4*)&((float*)out)[oi] = ov;
  } else {
    ushort4 ov;
    ov.x = f2us(v[0]); ov.y = f2us(v[1]); ov.z = f2us(v[2]); ov.w = f2us(v[3]);
    *(ushort4*)&((u16*)out)[oi] = ov;
  }
}

// ---------------------------------------------------------------------------
extern "C" void kernel_launch(void* const* d_in, const int* in_sizes, int n_in,
                              void* d_out, int out_size, void* d_ws, size_t ws_size,
                              hipStream_t stream)
{
  const int NA = in_sizes[0] / IN_F;   // 100000
  const int NP = in_sizes[1] / IN_F;   // 200000
  const int E_w = in_sizes[2], E_wb = in_sizes[4], E_c = in_sizes[6];

  const void* x_a   = d_in[0];
  const void* x_p   = d_in[1];
  const int* w_src  = (const int*)d_in[2];
  const int* w_dst  = (const int*)d_in[3];
  const int* wb_src = (const int*)d_in[4];
  const int* wb_dst = (const int*)d_in[5];
  const int* c_src  = (const int*)d_in[6];
  const int* c_dst  = (const int*)d_in[7];
  const void* W_pa  = d_in[8];
  const void* b_pa  = d_in[9];
  const void* W_pp  = d_in[10];
  const void* b_pp  = d_in[11];
  const void* at_s_w  = d_in[12];
  const void* at_d_w  = d_in[13];
  const void* at_s_wb = d_in[14];
  const void* at_d_wb = d_in[15];
  const void* at_s_c  = d_in[16];
  const void* at_d_c  = d_in[17];
  const void* W_k   = d_in[18];
  const void* b_k   = d_in[19];
  const void* q     = d_in[20];
  const void* W_lin = d_in[21];
  const void* b_lin = d_in[22];

  // ---- workspace layout: fixed region (~150 MB) + chunked o accumulator ----
  char* ws = (char*)d_ws;
  size_t off = 0;
  auto alloc = [&](size_t bytes) -> void* {
    void* p = ws + off;
    off += (bytes + 255) & ~(size_t)255;
    return p;
  };
  int*   flag_f = (int*)alloc(4);
  int*   flag_i = (int*)alloc(4);
  float* attn   = (float*)alloc(8 * 4);
  float* S      = (float*)alloc(2 * HID * 4);
  u32*   m_enc  = (u32*)alloc((size_t)NP * HEADS * 4);
  float* den    = (float*)alloc((size_t)NP * HEADS * 4);
  u16*   h_a    = (u16*)alloc((size_t)NA * HID * 2);
  u16*   h_p    = (u16*)alloc((size_t)NP * HID * 2);
  float* aA_ws  = (float*)alloc((size_t)NA * HEADS * 4);
  float* aA_wbd = (float*)alloc((size_t)NA * HEADS * 4);
  float* aP_wd  = (float*)alloc((size_t)NP * HEADS * 4);
  float* aP_wbs = (float*)alloc((size_t)NP * HEADS * 4);
  float* aP_cs  = (float*)alloc((size_t)NP * HEADS * 4);
  float* aP_cd  = (float*)alloc((size_t)NP * HEADS * 4);
  u16*   Pw16   = (u16*)alloc((size_t)NP * OUT_F * 2);
  u16*   Pc16   = (u16*)alloc((size_t)NP * OUT_F * 2);
  float* o_f32  = (float*)(ws + off);           // rest of ws, chunked
  size_t o_bytes = (ws_size > off) ? (ws_size - off) : 0;
  long long cap = (long long)(o_bytes / ((size_t)HID * 4));
  int rc = (int)(cap > NP ? NP : cap);
  rc &= ~63;                                     // multiple of 64
  if (rc < 64) rc = 64;                          // last resort; assume ws ok
  const size_t mden_bytes = ((size_t)NP * HEADS * 4) * 2;  // m_enc+den contiguous

  // ---- detection ----
  detect_float_width<<<1, 256, 0, stream>>>((const u16*)x_a, 4096, flag_f);
  detect_idx_width<<<1, 256, 0, stream>>>(w_src, 512, flag_i);

  // ---- projections + logits ----
  proj_kernel<<<(NA + 31) / 32, 256, 0, stream>>>(x_a, W_pa, b_pa, h_a, NA, flag_f);
  proj_kernel<<<(NP + 31) / 32, 256, 0, stream>>>(x_p, W_pp, b_pp, h_p, NP, flag_f);
  compute_a2<<<(NA * HEADS + 255) / 256, 256, 0, stream>>>(h_a, at_s_w, at_d_wb, aA_ws, aA_wbd, NA, flag_f);
  compute_a2<<<(NP * HEADS + 255) / 256, 256, 0, stream>>>(h_p, at_d_w, at_s_wb, aP_wd, aP_wbs, NP, flag_f);
  compute_a2<<<(NP * HEADS + 255) / 256, 256, 0, stream>>>(h_p, at_s_c, at_d_c, aP_cs, aP_cd, NP, flag_f);

  hipMemsetAsync(S, 0, 2 * HID * 4, stream);

  // ---- writtenby: paper -> author (direct author output) ----
  hipMemsetAsync(m_enc, 0, mden_bytes, stream);
  edge_pass1<<<(E_wb * HEADS + 255) / 256, 256, 0, stream>>>(wb_src, wb_dst, aP_wbs, aA_wbd, m_enc, E_wb * HEADS, flag_i, NP, NA);
  edge_pass2<<<(E_wb * HEADS + 255) / 256, 256, 0, stream>>>(wb_src, wb_dst, aP_wbs, aA_wbd, m_enc, den, E_wb * HEADS, flag_i, NP, NA);
  for (int lo = 0; lo < NA; lo += rc) {
    int rows = (NA - lo < rc) ? (NA - lo) : rc;
    hipMemsetAsync(o_f32, 0, (size_t)rows * HID * 4, stream);
    edge_pass3<<<((long long)E_wb * 64 + 255) / 256, 256, 0, stream>>>(wb_src, wb_dst, aP_wbs, aA_wbd, m_enc, den, h_p, o_f32, E_wb, flag_i, NP, NA, lo, lo + rows);
    final_author_chunk<<<(rows + 63) / 64, 256, 0, stream>>>(o_f32, rows, lo, W_lin, b_lin, d_out, flag_f);
  }

  // ---- writes: author -> paper (S0 colsum + Pw) ----
  hipMemsetAsync(m_enc, 0, mden_bytes, stream);
  edge_pass1<<<(E_w * HEADS + 255) / 256, 256, 0, stream>>>(w_src, w_dst, aA_ws, aP_wd, m_enc, E_w * HEADS, flag_i, NA, NP);
  edge_pass2<<<(E_w * HEADS + 255) / 256, 256, 0, stream>>>(w_src, w_dst, aA_ws, aP_wd, m_enc, den, E_w * HEADS, flag_i, NA, NP);
  for (int lo = 0; lo < NP; lo += rc) {
    int rows = (NP - lo < rc) ? (NP - lo) : rc;
    hipMemsetAsync(o_f32, 0, (size_t)rows * HID * 4, stream);
    edge_pass3<<<((long long)E_w * 64 + 255) / 256, 256, 0, stream>>>(w_src, w_dst, aA_ws, aP_wd, m_enc, den, h_a, o_f32, E_w, flag_i, NA, NP, lo, lo + rows);
    colsum_chunk<<<512, 256, 0, stream>>>(o_f32, rows, W_k, b_k, S, flag_f);
    linW_chunk<<<(rows + 63) / 64, 256, 0, stream>>>(o_f32, rows, W_lin, Pw16 + (size_t)lo * OUT_F, flag_f);
  }

  // ---- cites: paper -> paper (S1 colsum + Pc) ----
  hipMemsetAsync(m_enc, 0, mden_bytes, stream);
  edge_pass1<<<(E_c * HEADS + 255) / 256, 256, 0, stream>>>(c_src, c_dst, aP_cs, aP_cd, m_enc, E_c * HEADS, flag_i, NP, NP);
  edge_pass2<<<(E_c * HEADS + 255) / 256, 256, 0, stream>>>(c_src, c_dst, aP_cs, aP_cd, m_enc, den, E_c * HEADS, flag_i, NP, NP);
  for (int lo = 0; lo < NP; lo += rc) {
    int rows = (NP - lo < rc) ? (NP - lo) : rc;
    hipMemsetAsync(o_f32, 0, (size_t)rows * HID * 4, stream);
    edge_pass3<<<((long long)E_c * 64 + 255) / 256, 256, 0, stream>>>(c_src, c_dst, aP_cs, aP_cd, m_enc, den, h_p, o_f32, E_c, flag_i, NP, NP, lo, lo + rows);
    colsum_chunk<<<512, 256, 0, stream>>>(o_f32, rows, W_k, b_k, S + HID, flag_f);
    linW_chunk<<<(rows + 63) / 64, 256, 0, stream>>>(o_f32, rows, W_lin, Pc16 + (size_t)lo * OUT_F, flag_f);
  }

  // ---- semantic softmax + paper output ----
  score_softmax<<<1, 64, 0, stream>>>(S, q, attn, 1.0f / (float)NP, flag_f);
  combine_paper<<<((size_t)NP * 16 + 255) / 256, 256, 0, stream>>>(Pw16, Pc16, attn, b_lin, d_out, (size_t)NA * OUT_F, NP, flag_f);
}